// Round 1
// 892.864 us; speedup vs baseline: 1.0734x; 1.0734x over previous
//
#include <hip/hip_runtime.h>

// AddDecomposedRelativePositions, two-phase:
//
//  Phase A (relgemm_kernel): precompute the decomposed bias terms
//     RelH[b,h,w,kh] = dot(q[b,h,w,:], rph[h-kh+63,:])
//     RelW[b,h,w,kw] = dot(q[b,h,w,:], rpw[w-kw+63,:])
//   as 512 tiny 64x64x64 fp32 GEMMs. Table rows needed by a block are
//   CONTIGUOUS (x..x+63 -> one coalesced 16 KB stage), held transposed in
//   LDS with +1 padding (conflict-free reads: bank = (c + 63-lane) % 32).
//   Total: 16 MB written to workspace, ~268 MFLOP.
//
//  Phase B (stream_kernel): barrier-free pure streaming
//     out[r, kh*64+kw] = attn[r, ...] + RelH[r,kh] + RelW[r,kw]
//   The per-row 256 B bias vectors are L1-resident broadcast loads; the
//   kernel is otherwise a straight float4 copy-with-add and should run at
//   copy bandwidth (~6.2 TB/s like the harness fill kernel).

__global__ __launch_bounds__(256) void
relgemm_kernel(const float* __restrict__ q,
               const float* __restrict__ rph,
               const float* __restrict__ rpw,
               float* __restrict__ relH,
               float* __restrict__ relW)
{
    const int nPairH = gridDim.x >> 1;            // B * 64
    const int bid    = blockIdx.x;
    const bool isH   = bid < nPairH;
    const int pair   = isH ? bid : bid - nPairH;
    const int b      = pair >> 6;
    const int x      = pair & 63;                 // h for RelH, w for RelW
    const float* __restrict__ tab = isH ? rph : rpw;
    float* __restrict__ dst       = isH ? relH : relW;

    // s_T[c][i] = tab[(x+i)*64 + c]   (transposed, padded: conflict-free)
    __shared__ float s_T[64][65];

    for (int e = threadIdx.x; e < 4096; e += 256) {
        const int i = e >> 6;                     // row offset 0..63
        const int c = e & 63;                     // channel
        s_T[c][i] = tab[((x + i) << 6) + c];      // coalesced read; 2-way LDS write (free)
    }
    __syncthreads();

    const int wave = threadIdx.x >> 6;
    const int lane = threadIdx.x & 63;            // lane = output k index
    const int ti   = 63 - lane;                   // table tile index: row x + 63 - k

    #pragma unroll 2
    for (int yy = 0; yy < 16; ++yy) {
        const int y = (wave << 4) + yy;           // y = w for RelH, h for RelW
        const int row = isH ? ((b << 12) + (x << 6) + y)    // (b, h=x, w=y)
                            : ((b << 12) + (y << 6) + x);   // (b, h=y, w=x)
        const float4* __restrict__ q4 = (const float4*)(q + ((size_t)row << 6));

        float a0 = 0.f, a1 = 0.f, a2 = 0.f, a3 = 0.f;
        #pragma unroll
        for (int c4 = 0; c4 < 16; ++c4) {
            const float4 qv = q4[c4];             // wave-uniform addr -> 1-line broadcast
            a0 += qv.x * s_T[4 * c4 + 0][ti];
            a1 += qv.y * s_T[4 * c4 + 1][ti];
            a2 += qv.z * s_T[4 * c4 + 2][ti];
            a3 += qv.w * s_T[4 * c4 + 3][ti];
        }
        dst[((size_t)row << 6) + lane] = (a0 + a1) + (a2 + a3);   // coalesced 256 B
    }
}

__global__ __launch_bounds__(256) void
stream_kernel(const float* __restrict__ attn,
              const float* __restrict__ relH,
              const float* __restrict__ relW,
              float* __restrict__ out)
{
    const size_t r   = blockIdx.x;                // row (b,h,w) in [0, B*4096)
    const int    tid = threadIdx.x;

    const float4* __restrict__ attn4 = (const float4*)(attn + (r << 12));
    float4*       __restrict__ out4  = (float4*)(out + (r << 12));
    const float*  __restrict__ rh    = relH + (r << 6);
    const float4* __restrict__ rw4   = (const float4*)(relW + (r << 6));

    #pragma unroll
    for (int k = 0; k < 4; ++k) {
        const int i = tid + (k << 8);             // float4 index 0..1023
        const float  rhv = rh[i >> 4];            // kh = (4i)>>6; 4 addrs/wave, L1-hit
        const float4 rwv = rw4[i & 15];           // kw group; 256 B/wave, L1-hit
        float4 a = attn4[i];
        a.x += rhv + rwv.x;
        a.y += rhv + rwv.y;
        a.z += rhv + rwv.z;
        a.w += rhv + rwv.w;
        out4[i] = a;
    }
}

// ---- fallback: previous fused kernel (used only if workspace is too small) ----
__global__ __launch_bounds__(256) void
addrel_kernel(const float* __restrict__ attn,
              const float* __restrict__ q,
              const float* __restrict__ rph,
              const float* __restrict__ rpw,
              float* __restrict__ out)
{
    const int r   = blockIdx.x;
    const int hw  = r & 4095;
    const int h   = hw >> 6;
    const int w   = hw & 63;
    const int tid = threadIdx.x;

    __shared__ __align__(16) float s_q[64];
    __shared__ __align__(16) float s_rh[64];
    __shared__ __align__(16) float s_rw[64];

    if (tid < 64) s_q[tid] = q[(size_t)r * 64 + tid];
    __syncthreads();

    if (tid < 128) {
        const int   k    = tid & 63;
        const bool  isH  = (tid < 64);
        const float* tab = isH ? rph : rpw;
        const int   base = ((isH ? h : w) - k + 63) << 6;
        const float4* row4 = (const float4*)(tab + base);
        const float4* q4   = (const float4*)s_q;
        float acc = 0.f;
        #pragma unroll
        for (int c = 0; c < 16; ++c) {
            float4 a = row4[c];
            float4 b = q4[c];
            acc += a.x * b.x + a.y * b.y + a.z * b.z + a.w * b.w;
        }
        if (isH) s_rh[k] = acc;
        else     s_rw[k] = acc;
    }
    __syncthreads();

    const float4* attn4 = (const float4*)(attn + (size_t)r * 4096);
    float4*       out4  = (float4*)(out + (size_t)r * 4096);
    const float4* rw4   = (const float4*)s_rw;

    #pragma unroll
    for (int i = tid; i < 1024; i += 256) {
        const int   idx = i << 2;
        const float rhv = s_rh[idx >> 6];
        const float4 rw = rw4[(idx & 63) >> 2];
        float4 a = attn4[i];
        a.x += rhv + rw.x;
        a.y += rhv + rw.y;
        a.z += rhv + rw.z;
        a.w += rhv + rw.w;
        out4[i] = a;
    }
}

extern "C" void kernel_launch(void* const* d_in, const int* in_sizes, int n_in,
                              void* d_out, int out_size, void* d_ws, size_t ws_size,
                              hipStream_t stream) {
    const float* attn = (const float*)d_in[0];
    const float* q    = (const float*)d_in[1];
    const float* rph  = (const float*)d_in[2];
    const float* rpw  = (const float*)d_in[3];
    float* out = (float*)d_out;

    // in_sizes are element counts: attn has rows * 4096 floats, rows = B*64*64
    const int    rows     = in_sizes[0] / 4096;
    const size_t relElems = (size_t)rows * 64;

    if (ws_size >= 2 * relElems * sizeof(float)) {
        float* relH = (float*)d_ws;
        float* relW = relH + relElems;
        const int B = rows >> 12;
        relgemm_kernel<<<2 * B * 64, 256, 0, stream>>>(q, rph, rpw, relH, relW);
        stream_kernel<<<rows, 256, 0, stream>>>(attn, relH, relW, out);
    } else {
        addrel_kernel<<<rows, 256, 0, stream>>>(attn, q, rph, rpw, out);
    }
}